// Round 7
// 493.574 us; speedup vs baseline: 1.0559x; 1.0559x over previous
//
#include <hip/hip_runtime.h>
#include <math.h>

// Problem constants: x [B=16, C=64, H=256, W=256] fp32
#define BB   16
#define CC   64
#define HH_  256
#define WW_  256
#define HW   (HH_ * WW_)        // 65536
#define CHW  (CC * HW)          // 4194304
#define NPIX (BB * HW)          // 1048576
#define N4   (NPIX / 4)         // 262144 threads, 4 pixels each

// Native clang vector type: __builtin_nontemporal_load/store require a real
// vector type, not HIP's float4 class.
typedef float vfloat4 __attribute__((ext_vector_type(4)));

// Kernel 1: channel mean + channel max -> avg plane, max plane (each B*HW floats)
// Normal (cached) loads on purpose: this pass warms the 256 MiB Infinity Cache
// with x so the second kernel can re-read it from L3.
__global__ __launch_bounds__(256) void pool_kernel(const float* __restrict__ x,
                                                   float* __restrict__ avgp,
                                                   float* __restrict__ maxp) {
    int idx = blockIdx.x * blockDim.x + threadIdx.x;   // [0, N4)
    int b  = idx >> 14;                                // / (HW/4)
    int p4 = idx & 16383;                              // float4 index within plane

    const float4* x4 = (const float4*)x + (size_t)b * (CHW / 4) + p4;

    float4 s = {0.f, 0.f, 0.f, 0.f};
    float4 m = {-INFINITY, -INFINITY, -INFINITY, -INFINITY};
    #pragma unroll 8
    for (int c = 0; c < CC; ++c) {
        float4 v = x4[c * (HW / 4)];
        s.x += v.x; s.y += v.y; s.z += v.z; s.w += v.w;
        m.x = fmaxf(m.x, v.x); m.y = fmaxf(m.y, v.y);
        m.z = fmaxf(m.z, v.z); m.w = fmaxf(m.w, v.w);
    }
    const float inv = 1.0f / 64.0f;
    float4 a = {s.x * inv, s.y * inv, s.z * inv, s.w * inv};
    ((float4*)avgp)[idx] = a;
    ((float4*)maxp)[idx] = m;
}

// Kernel 2: 7x7 conv (avg,max planes) + bias + sigmoid, then out = x * att
// One thread = 4 consecutive pixels; one wave = one full 256-px row (h wave-uniform).
//
// Block order is REVERSED vs pool_kernel: pool streamed x forward through the
// 256 MiB L3, so the tail of x is the freshest cached data. Walking backwards
// chases the MRU frontier -> the 256 MiB x re-read hits L3 instead of HBM.
// out-stores and x-loads are non-temporal so this dead/write-once traffic does
// not evict the x lines still pending re-read.
__global__ __launch_bounds__(256) void conv_scale_kernel(const float* __restrict__ x,
                                                         const float* __restrict__ avgp,
                                                         const float* __restrict__ maxp,
                                                         const float* __restrict__ cw,
                                                         const float* __restrict__ cb,
                                                         float* __restrict__ out) {
    __shared__ float sw[99];                 // [0..48] avg taps, [49..97] max taps, [98] bias
    if (threadIdx.x < 99)
        sw[threadIdx.x] = (threadIdx.x < 98) ? cw[threadIdx.x] : cb[0];
    __syncthreads();

    int bid = gridDim.x - 1 - blockIdx.x;               // reverse traversal (L3 MRU chase)
    int idx = bid * blockDim.x + threadIdx.x;           // [0, N4)
    int b   = idx >> 14;
    int p4  = idx & 16383;
    int pix = p4 << 2;                                  // pixel index in plane
    int h   = pix >> 8;                                 // row (wave-uniform)
    int q   = p4 & 63;                                  // w0/4  (w0 = q*4)

    const float* ap = avgp + b * HW;
    const float* mp = maxp + b * HW;

    float bias = sw[98];
    float acc0 = bias, acc1 = bias, acc2 = bias, acc3 = bias;

    for (int dy = -3; dy <= 3; ++dy) {
        int hh = h + dy;
        if (hh < 0 || hh >= HH_) continue;              // zero row padding
        const float4* a4 = (const float4*)(ap + hh * WW_);
        const float4* m4 = (const float4*)(mp + hh * WW_);
        const float4 z = {0.f, 0.f, 0.f, 0.f};
        // cols w0-4 .. w0+7 (12 values); col<0 / col>=W are zero padding
        float4 aL = (q > 0)  ? a4[q - 1] : z;
        float4 aC = a4[q];
        float4 aR = (q < 63) ? a4[q + 1] : z;
        float4 mL = (q > 0)  ? m4[q - 1] : z;
        float4 mC = m4[q];
        float4 mR = (q < 63) ? m4[q + 1] : z;
        float av[12] = {aL.x, aL.y, aL.z, aL.w, aC.x, aC.y, aC.z, aC.w, aR.x, aR.y, aR.z, aR.w};
        float mv[12] = {mL.x, mL.y, mL.z, mL.w, mC.x, mC.y, mC.z, mC.w, mR.x, mR.y, mR.z, mR.w};

        const float* wr = sw + (dy + 3) * 7;            // avg taps row; +49 for max taps
        #pragma unroll
        for (int kx = 0; kx < 7; ++kx) {
            float wa = wr[kx];
            float wm = wr[49 + kx];
            int t = 1 + kx;                              // av index = j + (kx-3) + 4
            acc0 = fmaf(av[t + 0], wa, acc0);  acc0 = fmaf(mv[t + 0], wm, acc0);
            acc1 = fmaf(av[t + 1], wa, acc1);  acc1 = fmaf(mv[t + 1], wm, acc1);
            acc2 = fmaf(av[t + 2], wa, acc2);  acc2 = fmaf(mv[t + 2], wm, acc2);
            acc3 = fmaf(av[t + 3], wa, acc3);  acc3 = fmaf(mv[t + 3], wm, acc3);
        }
    }

    float att0 = 1.f / (1.f + __expf(-acc0));
    float att1 = 1.f / (1.f + __expf(-acc1));
    float att2 = 1.f / (1.f + __expf(-acc2));
    float att3 = 1.f / (1.f + __expf(-acc3));

    const vfloat4* xb = (const vfloat4*)x + (size_t)b * (CHW / 4) + p4;
    vfloat4*       ob = (vfloat4*)out     + (size_t)b * (CHW / 4) + p4;
    #pragma unroll 4
    for (int c = 0; c < CC; ++c) {
        vfloat4 v = __builtin_nontemporal_load(xb + c * (HW / 4));  // x dead after this
        vfloat4 r;
        r.x = v.x * att0; r.y = v.y * att1; r.z = v.z * att2; r.w = v.w * att3;
        __builtin_nontemporal_store(r, ob + c * (HW / 4));          // out never re-read
    }
}

extern "C" void kernel_launch(void* const* d_in, const int* in_sizes, int n_in,
                              void* d_out, int out_size, void* d_ws, size_t ws_size,
                              hipStream_t stream) {
    const float* x  = (const float*)d_in[0];
    const float* cw = (const float*)d_in[1];   // [1,2,7,7] = 98 floats
    const float* cb = (const float*)d_in[2];   // [1]
    float* out = (float*)d_out;

    float* avgp = (float*)d_ws;                // B*HW floats
    float* maxp = avgp + NPIX;                 // B*HW floats

    dim3 block(256);
    dim3 grid(N4 / 256);                       // 1024 blocks
    pool_kernel<<<grid, block, 0, stream>>>(x, avgp, maxp);
    conv_scale_kernel<<<grid, block, 0, stream>>>(x, avgp, maxp, cw, cb, out);
}